// Round 2
// baseline (7096.298 us; speedup 1.0000x reference)
//
#include <hip/hip_runtime.h>
#include <hip/hip_bf16.h>

namespace {

constexpr int kB = 1024;
constexpr int kT = 256;
constexpr int kH = 128;
constexpr int kS = 6;

// tanh(x) = 1 - 2/(exp(2x)+1); saturates correctly for |x| large.
__device__ __forceinline__ float fast_tanh(float x) {
    float e = __expf(2.0f * x);
    return 1.0f - 2.0f * __builtin_amdgcn_rcpf(e + 1.0f);
}

// One dyn() evaluation for one batch row, executed by one 64-lane wave.
// yc[] is lane-uniform; result d[] is lane-uniform.
__device__ __forceinline__ void dyn_eval(
    float t, const float yc[kS], float m, float v,
    float* __restrict__ hs, float* __restrict__ xs, int lane,
    const float* __restrict__ W_in, const float* __restrict__ b_in,
    const float* __restrict__ W_h,  const float* __restrict__ b_h,
    const float* __restrict__ W_out,const float* __restrict__ b_out,
    float d[kS])
{
    const int l31 = lane & 31;
    const int kh  = (lane >> 5) * 64;   // 0 or 64: split-K across wave halves

    // x = [t, y0..y5, y3, v]  (9 features) -> LDS, written by lane 0
    if (lane == 0) {
        xs[0] = t;     xs[1] = yc[0]; xs[2] = yc[1]; xs[3] = yc[2];
        xs[4] = yc[3]; xs[5] = yc[4]; xs[6] = yc[5]; xs[7] = yc[3]; xs[8] = v;
    }

    // ---- input layer: h[j] = tanh(sum_k x[k] W_in[k][j] + b_in[j]), K=9
    // every lane computes j = 4*l31 .. 4*l31+3 over full K (halves redundant)
    const float4* Wi4 = (const float4*)W_in;
    float4 a = ((const float4*)b_in)[l31];
    #pragma unroll
    for (int k = 0; k < 9; ++k) {
        float xv = xs[k];
        float4 w = Wi4[k*32 + l31];
        a.x += xv*w.x; a.y += xv*w.y; a.z += xv*w.z; a.w += xv*w.w;
    }
    a.x = fast_tanh(a.x); a.y = fast_tanh(a.y);
    a.z = fast_tanh(a.z); a.w = fast_tanh(a.w);
    if (lane < 32) ((float4*)hs)[l31] = a;

    // ---- 3 hidden layers, K=128 split across the two wave halves
    #pragma unroll
    for (int l = 0; l < 3; ++l) {
        const float4* W4 = (const float4*)(W_h + l*kH*kH);
        float4 acc = make_float4(0.f, 0.f, 0.f, 0.f);
        #pragma unroll 8
        for (int kk = 0; kk < 64; ++kk) {
            float  hk = hs[kh + kk];
            float4 w  = W4[(kh + kk)*32 + l31];
            acc.x += hk*w.x; acc.y += hk*w.y; acc.z += hk*w.z; acc.w += hk*w.w;
        }
        acc.x += __shfl_xor(acc.x, 32);
        acc.y += __shfl_xor(acc.y, 32);
        acc.z += __shfl_xor(acc.z, 32);
        acc.w += __shfl_xor(acc.w, 32);
        float4 bb = ((const float4*)(b_h + l*kH))[l31];
        acc.x = fast_tanh(acc.x + bb.x);
        acc.y = fast_tanh(acc.y + bb.y);
        acc.z = fast_tanh(acc.z + bb.z);
        acc.w = fast_tanh(acc.w + bb.w);
        if (lane < 32) ((float4*)hs)[l31] = acc;   // in-order per-wave DS: safe
    }

    // ---- output layer 128->6: lane handles k=lane and k=lane+64, butterfly
    float ha = hs[lane], hb = hs[lane + 64];
    float p[kS];
    #pragma unroll
    for (int s = 0; s < kS; ++s)
        p[s] = ha * W_out[lane*kS + s] + hb * W_out[(lane + 64)*kS + s];
    #pragma unroll
    for (int off = 32; off >= 1; off >>= 1) {
        #pragma unroll
        for (int s = 0; s < kS; ++s) p[s] += __shfl_xor(p[s], off);
    }

    // ---- ODE core + residual (lane-uniform)
    const float G = yc[0], I = yc[1], N = yc[2], L = yc[3], GE = yc[4], F = yc[5];
    d[0] = -0.01f*I*G + 0.05f*GE                                  + (p[0] + b_out[0]);
    d[1] = (G / (100.0f + G)) * (1.0f + 2.0f*L/(5.0f + L)) - 0.1f*I + (p[1] + b_out[1]);
    d[2] = -0.05f*N                                                + (p[2] + b_out[2]);
    d[3] = 0.05f*GE - 0.2f*L                                       + (p[3] + b_out[3]);
    d[4] = m - 0.05f*GE                                            + (p[4] + b_out[4]);
    d[5] = -0.01f*I*F                                              + (p[5] + b_out[5]);
}

__global__ __launch_bounds__(256, 1) void hybrid_ode_kernel(
    const float* __restrict__ y0,
    const float* __restrict__ t_span,
    const float* __restrict__ meal,
    const float* __restrict__ tvns,
    const float* __restrict__ W_in, const float* __restrict__ b_in,
    const float* __restrict__ W_h,  const float* __restrict__ b_h,
    const float* __restrict__ W_out,const float* __restrict__ b_out,
    float* __restrict__ out)
{
    const int wave = threadIdx.x >> 6;
    const int lane = threadIdx.x & 63;
    const int row  = blockIdx.x * 4 + wave;   // one wave per batch row

    __shared__ __align__(16) float h_s[4][kH];
    __shared__ __align__(16) float x_s[4][12];
    float* hs = h_s[wave];
    float* xs = x_s[wave];

    // lane-uniform RK4 state
    float y[kS];
    #pragma unroll
    for (int s = 0; s < kS; ++s) y[s] = y0[row*kS + s];

    if (lane == 0) {
        #pragma unroll
        for (int s = 0; s < kS; ++s)
            out[(size_t)row*kT*kS + s] = y[s];
    }

    const float* mrow = meal + (size_t)row*kT;
    const float* vrow = tvns + (size_t)row*kT;

    for (int i = 0; i < kT - 1; ++i) {
        float t0 = t_span[i], t1 = t_span[i+1];
        float dt = t1 - t0;
        float m0 = mrow[i], m1 = mrow[i+1];
        float v0 = vrow[i], v1 = vrow[i+1];
        float tm = t0 + 0.5f*dt;
        float mm = 0.5f*(m0 + m1), vm = 0.5f*(v0 + v1);

        float k1[kS], k2[kS], k3[kS], k4[kS], yc[kS];

        dyn_eval(t0, y,  m0, v0, hs, xs, lane, W_in,b_in,W_h,b_h,W_out,b_out, k1);
        #pragma unroll
        for (int s = 0; s < kS; ++s) yc[s] = y[s] + 0.5f*dt*k1[s];
        dyn_eval(tm, yc, mm, vm, hs, xs, lane, W_in,b_in,W_h,b_h,W_out,b_out, k2);
        #pragma unroll
        for (int s = 0; s < kS; ++s) yc[s] = y[s] + 0.5f*dt*k2[s];
        dyn_eval(tm, yc, mm, vm, hs, xs, lane, W_in,b_in,W_h,b_h,W_out,b_out, k3);
        #pragma unroll
        for (int s = 0; s < kS; ++s) yc[s] = y[s] + dt*k3[s];
        dyn_eval(t1, yc, m1, v1, hs, xs, lane, W_in,b_in,W_h,b_h,W_out,b_out, k4);
        #pragma unroll
        for (int s = 0; s < kS; ++s)
            y[s] += (dt*(1.0f/6.0f))*(k1[s] + 2.0f*k2[s] + 2.0f*k3[s] + k4[s]);

        if (lane == 0) {
            #pragma unroll
            for (int s = 0; s < kS; ++s)
                out[((size_t)row*kT + (i+1))*kS + s] = y[s];
        }
    }
}

} // namespace

extern "C" void kernel_launch(void* const* d_in, const int* in_sizes, int n_in,
                              void* d_out, int out_size, void* d_ws, size_t ws_size,
                              hipStream_t stream) {
    const float* y0     = (const float*)d_in[0];
    const float* t_span = (const float*)d_in[1];
    const float* meal   = (const float*)d_in[2];
    const float* tvns   = (const float*)d_in[3];
    const float* W_in   = (const float*)d_in[4];
    const float* b_in   = (const float*)d_in[5];
    const float* W_h    = (const float*)d_in[6];
    const float* b_h    = (const float*)d_in[7];
    const float* W_out  = (const float*)d_in[8];
    const float* b_out  = (const float*)d_in[9];
    float* out          = (float*)d_out;

    hipLaunchKernelGGL(hybrid_ode_kernel, dim3(kB/4), dim3(256), 0, stream,
                       y0, t_span, meal, tvns,
                       W_in, b_in, W_h, b_h, W_out, b_out, out);
}

// Round 3
// 4212.590 us; speedup vs baseline: 1.6845x; 1.6845x over previous
//
#include <hip/hip_runtime.h>

namespace {

constexpr int kT = 256;
constexpr int kS = 6;

__device__ __forceinline__ float fast_tanh(float x) {
    float e = __expf(2.0f * x);
    return 1.0f - 2.0f * __builtin_amdgcn_rcpf(e + 1.0f);
}

// Butterfly sum over the 4 lanes of a quad (DPP quad_perm, VALU-rate).
// All 4 lanes end up holding the quad sum.
__device__ __forceinline__ float quad_reduce(float x) {
    int i = __builtin_bit_cast(int, x);
    int a = __builtin_amdgcn_update_dpp(0, i, 0xB1, 0xF, 0xF, true); // [1,0,3,2]
    float s = x + __builtin_bit_cast(float, a);
    int j = __builtin_bit_cast(int, s);
    int b = __builtin_amdgcn_update_dpp(0, j, 0x4E, 0xF, 0xF, true); // [2,3,0,1]
    return s + __builtin_bit_cast(float, b);
}

__global__ __launch_bounds__(512, 2) void hybrid_ode_kernel(
    const float* __restrict__ y0,
    const float* __restrict__ t_span,
    const float* __restrict__ meal,
    const float* __restrict__ tvns,
    const float* __restrict__ W_in, const float* __restrict__ b_in,
    const float* __restrict__ W_h,  const float* __restrict__ b_h,
    const float* __restrict__ W_out,const float* __restrict__ b_out,
    float* __restrict__ out)
{
    const int tid = threadIdx.x;
    const int w   = tid >> 6;        // wave 0..7
    const int l   = tid & 63;
    const int jg  = l >> 2;          // 0..15 : j-group (8 j's)
    const int kql = l & 3;           // 0..3  : k-group within quad
    const int kg  = w * 4 + kql;     // 0..31 : k-group (4 k's)
    const int j0  = jg * 8;
    const int k0  = kg * 4;
    const int j1  = tid & 127;       // phase-2 / input-layer column
    const int rr1 = tid >> 7;        // 0..3  : phase-2 row
    const int rw  = w & 3;           // row this wave carries (dup in w>=4)
    const int row = blockIdx.x * 4 + rw;

    __shared__ float part[8 * 4 * 128];   // [w][r][j] partials, 16 KB
    __shared__ float hbuf[4][128];        // activations per row
    __shared__ float xbuf[4][12];         // input features per row

    // ---- one-time: weights into registers
    float wgt[3][4][8];   // [layer][kk][jj] = W_h[layer][k0+kk][j0+jj]
    #pragma unroll
    for (int ll = 0; ll < 3; ++ll)
        #pragma unroll
        for (int kk = 0; kk < 4; ++kk) {
            const float* src = W_h + (size_t)(ll * 128 + k0 + kk) * 128 + j0;
            float4 a = *(const float4*)src;
            float4 b = *(const float4*)(src + 4);
            wgt[ll][kk][0]=a.x; wgt[ll][kk][1]=a.y; wgt[ll][kk][2]=a.z; wgt[ll][kk][3]=a.w;
            wgt[ll][kk][4]=b.x; wgt[ll][kk][5]=b.y; wgt[ll][kk][6]=b.z; wgt[ll][kk][7]=b.w;
        }
    float win[9];
    #pragma unroll
    for (int k = 0; k < 9; ++k) win[k] = W_in[k * 128 + j1];
    const float bin = b_in[j1];
    float bh[3];
    #pragma unroll
    for (int ll = 0; ll < 3; ++ll) bh[ll] = b_h[ll * 128 + j1];
    float wo_a[6], wo_b[6], bo[6];
    #pragma unroll
    for (int s = 0; s < 6; ++s) {
        wo_a[s] = W_out[l * 6 + s];
        wo_b[s] = W_out[(l + 64) * 6 + s];
        bo[s]   = b_out[s];
    }

    // ---- RK4 state (wave-local; waves rw and rw+4 hold identical copies)
    float y[6];
    #pragma unroll
    for (int s = 0; s < 6; ++s) y[s] = y0[row * 6 + s];

    if (w < 4 && l == 0) {
        #pragma unroll
        for (int s = 0; s < 6; ++s) out[(size_t)row * kT * 6 + s] = y[s];
    }

    const float* mrow = meal + (size_t)row * kT;
    const float* vrow = tvns + (size_t)row * kT;

    auto dyn = [&](float t, const float* yc, float m, float v, float* d) {
        // publish features for this wave's row
        if (w < 4 && l == 0) {
            float* xb = xbuf[w];
            xb[0]=t;     xb[1]=yc[0]; xb[2]=yc[1]; xb[3]=yc[2];
            xb[4]=yc[3]; xb[5]=yc[4]; xb[6]=yc[5]; xb[7]=yc[3]; xb[8]=v;
        }
        __syncthreads();

        // input layer 9->128 : one (j,row) output per thread, no reduction
        {
            float s = bin;
            #pragma unroll
            for (int k = 0; k < 9; ++k) s += xbuf[rr1][k] * win[k];
            hbuf[rr1][j1] = fast_tanh(s);
        }
        __syncthreads();

        // 3 hidden layers 128->128
        #pragma unroll
        for (int ll = 0; ll < 3; ++ll) {
            float hreg[4][4];
            #pragma unroll
            for (int r = 0; r < 4; ++r) {
                float4 hv = *(const float4*)&hbuf[r][k0];   // 4-addr broadcast
                hreg[r][0]=hv.x; hreg[r][1]=hv.y; hreg[r][2]=hv.z; hreg[r][3]=hv.w;
            }
            float acc[4][8];
            #pragma unroll
            for (int r = 0; r < 4; ++r)
                #pragma unroll
                for (int jj = 0; jj < 8; ++jj) acc[r][jj] = 0.0f;
            #pragma unroll
            for (int kk = 0; kk < 4; ++kk)
                #pragma unroll
                for (int r = 0; r < 4; ++r) {
                    const float hv = hreg[r][kk];
                    #pragma unroll
                    for (int jj = 0; jj < 8; ++jj)
                        acc[r][jj] += hv * wgt[ll][kk][jj];
                }
            // reduce over the quad (k-groups kql=0..3); lane kql keeps row kql
            float o[8];
            #pragma unroll
            for (int jj = 0; jj < 8; ++jj) {
                float s0 = quad_reduce(acc[0][jj]);
                float s1 = quad_reduce(acc[1][jj]);
                float s2 = quad_reduce(acc[2][jj]);
                float s3 = quad_reduce(acc[3][jj]);
                float sa = (kql & 1) ? s1 : s0;
                float sb = (kql & 1) ? s3 : s2;
                o[jj]    = (kql & 2) ? sb : sa;
            }
            float* pw = &part[(w * 4 + kql) * 128 + j0];
            *(float4*)pw       = make_float4(o[0], o[1], o[2], o[3]);
            *(float4*)(pw + 4) = make_float4(o[4], o[5], o[6], o[7]);
            __syncthreads();

            // cross-wave reduction: one (j,row) per thread
            float s8 = 0.0f;
            #pragma unroll
            for (int wv = 0; wv < 8; ++wv)
                s8 += part[(wv * 4 + rr1) * 128 + j1];
            hbuf[rr1][j1] = fast_tanh(s8 + bh[ll]);
            __syncthreads();
        }

        // output layer 128->6 for this wave's row (wave-wide butterfly)
        float ha = hbuf[rw][l];
        float hb = hbuf[rw][l + 64];
        float p[6];
        #pragma unroll
        for (int s = 0; s < 6; ++s) p[s] = ha * wo_a[s] + hb * wo_b[s];
        #pragma unroll
        for (int off = 32; off >= 1; off >>= 1) {
            #pragma unroll
            for (int s = 0; s < 6; ++s) p[s] += __shfl_xor(p[s], off);
        }

        const float G = yc[0], I = yc[1], N = yc[2], L = yc[3], GE = yc[4], F = yc[5];
        d[0] = -0.01f*I*G + 0.05f*GE                                    + p[0] + bo[0];
        d[1] = (G/(100.0f+G))*(1.0f + 2.0f*L/(5.0f+L)) - 0.1f*I         + p[1] + bo[1];
        d[2] = -0.05f*N                                                 + p[2] + bo[2];
        d[3] = 0.05f*GE - 0.2f*L                                        + p[3] + bo[3];
        d[4] = m - 0.05f*GE                                             + p[4] + bo[4];
        d[5] = -0.01f*I*F                                               + p[5] + bo[5];
    };

    for (int i = 0; i < kT - 1; ++i) {
        const float t0 = t_span[i], t1 = t_span[i + 1];
        const float dt = t1 - t0;
        const float m0 = mrow[i], m1 = mrow[i + 1];
        const float v0 = vrow[i], v1 = vrow[i + 1];
        const float tm = t0 + 0.5f * dt;
        const float mm = 0.5f * (m0 + m1), vm = 0.5f * (v0 + v1);

        float k1[6], k2[6], k3[6], k4[6], yc[6];

        dyn(t0, y,  m0, v0, k1);
        #pragma unroll
        for (int s = 0; s < 6; ++s) yc[s] = y[s] + 0.5f * dt * k1[s];
        dyn(tm, yc, mm, vm, k2);
        #pragma unroll
        for (int s = 0; s < 6; ++s) yc[s] = y[s] + 0.5f * dt * k2[s];
        dyn(tm, yc, mm, vm, k3);
        #pragma unroll
        for (int s = 0; s < 6; ++s) yc[s] = y[s] + dt * k3[s];
        dyn(t1, yc, m1, v1, k4);
        #pragma unroll
        for (int s = 0; s < 6; ++s)
            y[s] += (dt * (1.0f / 6.0f)) * (k1[s] + 2.0f * k2[s] + 2.0f * k3[s] + k4[s]);

        if (w < 4 && l == 0) {
            #pragma unroll
            for (int s = 0; s < 6; ++s)
                out[((size_t)row * kT + (i + 1)) * 6 + s] = y[s];
        }
    }
}

} // namespace

extern "C" void kernel_launch(void* const* d_in, const int* in_sizes, int n_in,
                              void* d_out, int out_size, void* d_ws, size_t ws_size,
                              hipStream_t stream) {
    const float* y0     = (const float*)d_in[0];
    const float* t_span = (const float*)d_in[1];
    const float* meal   = (const float*)d_in[2];
    const float* tvns   = (const float*)d_in[3];
    const float* W_in   = (const float*)d_in[4];
    const float* b_in   = (const float*)d_in[5];
    const float* W_h    = (const float*)d_in[6];
    const float* b_h    = (const float*)d_in[7];
    const float* W_out  = (const float*)d_in[8];
    const float* b_out  = (const float*)d_in[9];
    float* out          = (float*)d_out;

    hipLaunchKernelGGL(hybrid_ode_kernel, dim3(256), dim3(512), 0, stream,
                       y0, t_span, meal, tvns,
                       W_in, b_in, W_h, b_h, W_out, b_out, out);
}

// Round 5
// 3011.993 us; speedup vs baseline: 2.3560x; 1.3986x over previous
//
#include <hip/hip_runtime.h>

namespace {

constexpr int kT  = 256;
constexpr int kHS = 140;   // physical row stride: chunks at 0/36/72/108, 32 wide

__device__ __forceinline__ float fast_tanh(float x) {
    float e = __expf(2.0f * x);
    return 1.0f - 2.0f * __builtin_amdgcn_rcpf(e + 1.0f);
}

// Sum over the 4 lanes of a quad via DPP (VALU-rate); all lanes get the sum.
__device__ __forceinline__ float quad_reduce(float x) {
    int i = __builtin_bit_cast(int, x);
    int a = __builtin_amdgcn_update_dpp(0, i, 0xB1, 0xF, 0xF, true); // lane^1
    float s = x + __builtin_bit_cast(float, a);
    int j = __builtin_bit_cast(int, s);
    int b = __builtin_amdgcn_update_dpp(0, j, 0x4E, 0xF, 0xF, true); // lane^2
    return s + __builtin_bit_cast(float, b);
}

// x += x from lane^(xor) within each 32-lane half (ds_swizzle BitMode).
template <int PAT>
__device__ __forceinline__ float swz_add(float x) {
    int a = __builtin_amdgcn_ds_swizzle(__builtin_bit_cast(int, x), PAT);
    return x + __builtin_bit_cast(float, a);
}

// k -> physical offset within a row: chunk c=k>>5 starts at 36c (bank 4c).
__device__ __forceinline__ int hphys(int k) { return k + 4 * (k >> 5); }

__global__ __launch_bounds__(512, 2) void hybrid_ode_kernel(
    const float* __restrict__ y0,
    const float* __restrict__ t_span,
    const float* __restrict__ meal,
    const float* __restrict__ tvns,
    const float* __restrict__ W_in, const float* __restrict__ b_in,
    const float* __restrict__ W_h,  const float* __restrict__ b_h,
    const float* __restrict__ W_out,const float* __restrict__ b_out,
    float* __restrict__ out)
{
    const int tid = threadIdx.x;
    const int w   = tid >> 6;     // wave 0..7
    const int l   = tid & 63;
    const int jg  = l >> 2;       // 0..15
    const int kql = l & 3;        // k-chunk within quad (32 k's each)
    const int l31 = l & 31;
    const int j   = w * 16 + jg;  // this thread's output column (0..127)
    const int rw  = w & 3;        // row this wave carries (dup in w>=4)
    const int row = blockIdx.x * 4 + rw;
    const int widx = kql * kHS + hphys(j);   // h[row=kql][col=j]

    __shared__ __align__(16) float hb0[4 * kHS];
    __shared__ __align__(16) float hb1[4 * kHS];
    __shared__ float xbuf[4 * 16];

    // ---- one-time: weights into registers
    float wgt[3][32];   // wgt[ll][kk] = W_h[ll][kql*32+kk][j]
    #pragma unroll
    for (int ll = 0; ll < 3; ++ll)
        #pragma unroll
        for (int kk = 0; kk < 32; ++kk)
            wgt[ll][kk] = W_h[(size_t)(ll * 128 + kql * 32 + kk) * 128 + j];
    float win[9];
    #pragma unroll
    for (int k = 0; k < 9; ++k) win[k] = W_in[k * 128 + j];
    const float bin = b_in[j];
    float bh[3];
    #pragma unroll
    for (int ll = 0; ll < 3; ++ll) bh[ll] = b_h[ll * 128 + j];
    float wo[4][6], bo[6];
    #pragma unroll
    for (int c = 0; c < 4; ++c)
        #pragma unroll
        for (int s = 0; s < 6; ++s) wo[c][s] = W_out[(c * 32 + l31) * 6 + s];
    #pragma unroll
    for (int s = 0; s < 6; ++s) bo[s] = b_out[s];

    // ---- RK4 state (lane-uniform per wave; waves rw and rw+4 identical)
    float y[6];
    #pragma unroll
    for (int s = 0; s < 6; ++s) y[s] = y0[row * 6 + s];

    if (w < 4 && l == 0) {
        #pragma unroll
        for (int s = 0; s < 6; ++s) out[(size_t)row * kT * 6 + s] = y[s];
    }

    const float* mrow = meal + (size_t)row * kT;
    const float* vrow = tvns + (size_t)row * kT;

    auto dyn = [&](float t, const float* yc, float m, float v, float* d) {
        // publish features for this wave's row
        if (w < 4 && l == 0) {
            float* xb = &xbuf[w * 16];
            xb[0]=t;     xb[1]=yc[0]; xb[2]=yc[1]; xb[3]=yc[2];
            xb[4]=yc[3]; xb[5]=yc[4]; xb[6]=yc[5]; xb[7]=yc[3]; xb[8]=v;
        }
        __syncthreads();

        // input layer 9->128: thread -> (row=kql, col=j), no reduction
        {
            float s = bin;
            #pragma unroll
            for (int k = 0; k < 9; ++k) s += xbuf[kql * 16 + k] * win[k];
            hb0[widx] = fast_tanh(s);
        }
        __syncthreads();

        // 3 hidden layers 128->128, ping-pong hb0/hb1
        #pragma unroll
        for (int ll = 0; ll < 3; ++ll) {
            const float* rb = (ll & 1) ? hb1 : hb0;
            float*       wb = (ll & 1) ? hb0 : hb1;
            float a0 = 0.f, a1 = 0.f, a2 = 0.f, a3 = 0.f;
            #pragma unroll
            for (int q = 0; q < 8; ++q) {
                const int ko = 36 * kql + 4 * q;
                float4 h0 = *(const float4*)(rb + 0 * kHS + ko);
                float4 h1 = *(const float4*)(rb + 1 * kHS + ko);
                float4 h2 = *(const float4*)(rb + 2 * kHS + ko);
                float4 h3 = *(const float4*)(rb + 3 * kHS + ko);
                const float* wq = &wgt[ll][4 * q];
                a0 += h0.x*wq[0]; a0 += h0.y*wq[1]; a0 += h0.z*wq[2]; a0 += h0.w*wq[3];
                a1 += h1.x*wq[0]; a1 += h1.y*wq[1]; a1 += h1.z*wq[2]; a1 += h1.w*wq[3];
                a2 += h2.x*wq[0]; a2 += h2.y*wq[1]; a2 += h2.z*wq[2]; a2 += h2.w*wq[3];
                a3 += h3.x*wq[0]; a3 += h3.y*wq[1]; a3 += h3.z*wq[2]; a3 += h3.w*wq[3];
            }
            float s0 = quad_reduce(a0);
            float s1 = quad_reduce(a1);
            float s2 = quad_reduce(a2);
            float s3 = quad_reduce(a3);
            float hv = (kql == 0) ? s0 : (kql == 1) ? s1 : (kql == 2) ? s2 : s3;
            wb[widx] = fast_tanh(hv + bh[ll]);
            __syncthreads();
        }

        // output layer 128->6 for this wave's row; h lives in hb1
        float h0 = hb1[rw * kHS +   0 + l31];
        float h1 = hb1[rw * kHS +  36 + l31];
        float h2 = hb1[rw * kHS +  72 + l31];
        float h3 = hb1[rw * kHS + 108 + l31];
        float p[6];
        #pragma unroll
        for (int s = 0; s < 6; ++s) {
            float ps = h0 * wo[0][s];
            ps += h1 * wo[1][s];
            ps += h2 * wo[2][s];
            ps += h3 * wo[3][s];
            ps = quad_reduce(ps);          // xor1 + xor2 (DPP)
            ps = swz_add<0x101F>(ps);      // xor4
            ps = swz_add<0x201F>(ps);      // xor8
            ps = swz_add<0x401F>(ps);      // xor16 (halves are duplicates)
            p[s] = ps;
        }

        const float G = yc[0], I = yc[1], N = yc[2], L = yc[3], GE = yc[4], F = yc[5];
        d[0] = -0.01f*I*G + 0.05f*GE                                    + p[0] + bo[0];
        d[1] = (G/(100.0f+G))*(1.0f + 2.0f*L/(5.0f+L)) - 0.1f*I         + p[1] + bo[1];
        d[2] = -0.05f*N                                                 + p[2] + bo[2];
        d[3] = 0.05f*GE - 0.2f*L                                        + p[3] + bo[3];
        d[4] = m - 0.05f*GE                                             + p[4] + bo[4];
        d[5] = -0.01f*I*F                                               + p[5] + bo[5];
    };

    for (int i = 0; i < kT - 1; ++i) {
        const float t0 = t_span[i], t1 = t_span[i + 1];
        const float dt = t1 - t0;
        const float m0 = mrow[i], m1 = mrow[i + 1];
        const float v0 = vrow[i], v1 = vrow[i + 1];
        const float tm = t0 + 0.5f * dt;
        const float mm = 0.5f * (m0 + m1), vm = 0.5f * (v0 + v1);

        float k1[6], k2[6], k3[6], k4[6], yc[6];

        dyn(t0, y,  m0, v0, k1);
        #pragma unroll
        for (int s = 0; s < 6; ++s) yc[s] = y[s] + 0.5f * dt * k1[s];
        dyn(tm, yc, mm, vm, k2);
        #pragma unroll
        for (int s = 0; s < 6; ++s) yc[s] = y[s] + 0.5f * dt * k2[s];
        dyn(tm, yc, mm, vm, k3);
        #pragma unroll
        for (int s = 0; s < 6; ++s) yc[s] = y[s] + dt * k3[s];
        dyn(t1, yc, m1, v1, k4);
        #pragma unroll
        for (int s = 0; s < 6; ++s)
            y[s] += (dt * (1.0f / 6.0f)) * (k1[s] + 2.0f * k2[s] + 2.0f * k3[s] + k4[s]);

        if (w < 4 && l == 0) {
            #pragma unroll
            for (int s = 0; s < 6; ++s)
                out[((size_t)row * kT + (i + 1)) * 6 + s] = y[s];
        }
    }
}

} // namespace

extern "C" void kernel_launch(void* const* d_in, const int* in_sizes, int n_in,
                              void* d_out, int out_size, void* d_ws, size_t ws_size,
                              hipStream_t stream) {
    const float* y0     = (const float*)d_in[0];
    const float* t_span = (const float*)d_in[1];
    const float* meal   = (const float*)d_in[2];
    const float* tvns   = (const float*)d_in[3];
    const float* W_in   = (const float*)d_in[4];
    const float* b_in   = (const float*)d_in[5];
    const float* W_h    = (const float*)d_in[6];
    const float* b_h    = (const float*)d_in[7];
    const float* W_out  = (const float*)d_in[8];
    const float* b_out  = (const float*)d_in[9];
    float* out          = (float*)d_out;

    hipLaunchKernelGGL(hybrid_ode_kernel, dim3(256), dim3(512), 0, stream,
                       y0, t_span, meal, tvns,
                       W_in, b_in, W_h, b_h, W_out, b_out, out);
}

// Round 6
// 2897.716 us; speedup vs baseline: 2.4489x; 1.0394x over previous
//
#include <hip/hip_runtime.h>

namespace {

constexpr int kT = 256;

typedef float f2 __attribute__((ext_vector_type(2)));
typedef float f4 __attribute__((ext_vector_type(4)));

__device__ __forceinline__ float fast_tanh(float x) {
    float e = __expf(2.0f * x);
    return 1.0f - 2.0f * __builtin_amdgcn_rcpf(e + 1.0f);
}

__device__ __forceinline__ float dpp_xor1(float x) {
    return __builtin_bit_cast(float, __builtin_amdgcn_update_dpp(
        0, __builtin_bit_cast(int, x), 0xB1, 0xF, 0xF, true)); // quad [1,0,3,2]
}
__device__ __forceinline__ float dpp_xor2(float x) {
    return __builtin_bit_cast(float, __builtin_amdgcn_update_dpp(
        0, __builtin_bit_cast(int, x), 0x4E, 0xF, 0xF, true)); // quad [2,3,0,1]
}
template <int PAT>
__device__ __forceinline__ float swz(float x) {
    return __builtin_bit_cast(float,
        __builtin_amdgcn_ds_swizzle(__builtin_bit_cast(int, x), PAT));
}

// h storage: element (k2,r,b) at float offset 8*k2 + 4*(k2>>2) + 2*r + b,
// where k2 = k>>1, b = k&1. f2 pair (k even, k odd) is contiguous; the
// pad 4*(k2>>2) spreads kc-chunks across banks (<=2-way everywhere).
__device__ __forceinline__ int haddr(int j, int r) {
    return 8 * (j >> 1) + 4 * (j >> 3) + 2 * r + (j & 1);
}

__global__ __launch_bounds__(512, 2) void hybrid_ode_kernel(
    const float* __restrict__ y0,
    const float* __restrict__ t_span,
    const float* __restrict__ meal,
    const float* __restrict__ tvns,
    const float* __restrict__ W_in, const float* __restrict__ b_in,
    const float* __restrict__ W_h,  const float* __restrict__ b_h,
    const float* __restrict__ W_out,const float* __restrict__ b_out,
    float* __restrict__ out)
{
    const int tid = threadIdx.x;
    const int w   = tid >> 6;          // wave 0..7
    const int l   = tid & 63;
    const int jgl = l >> 4;            // 0..3 j-group within wave
    const int kc  = l & 15;            // k-chunk (8 k's)
    const int jg  = w * 4 + jgl;       // 0..31
    const int jb  = jg * 4;            // thread's 4 j's: jb..jb+3
    const int rw  = w & 3;             // RK row this wave carries
    const int row = blockIdx.x * 4 + rw;

    // produced output slot after reduce-scatter
    const int r_p = kc & 3;
    const int j_p = jb + (kc >> 2);
    const int waddr = haddr(j_p, r_p);
    const bool pb0 = (kc & 1) != 0;
    const bool pb1 = (kc & 2) != 0;
    const bool pb2 = (kc & 4) != 0;
    const bool pb3 = (kc & 8) != 0;

    __shared__ __align__(16) float hp0[576];
    __shared__ __align__(16) float hp1[576];
    __shared__ float xbuf[4 * 16];

    // ---- one-time weight staging into registers
    f2 wgt[3][4][4];   // [layer][kpair kappa][jj]: k = 8kc+2*kappa (+1)
    #pragma unroll
    for (int ll = 0; ll < 3; ++ll)
        #pragma unroll
        for (int ka = 0; ka < 4; ++ka)
            #pragma unroll
            for (int jj = 0; jj < 4; ++jj) {
                const float* p = W_h + (size_t)(ll * 128 + 8 * kc + 2 * ka) * 128 + jb + jj;
                f2 v; v.x = p[0]; v.y = p[128];
                wgt[ll][ka][jj] = v;
            }
    float win[9];
    #pragma unroll
    for (int k = 0; k < 9; ++k) win[k] = W_in[k * 128 + j_p];
    const float bin = b_in[j_p];
    float bh[3];
    #pragma unroll
    for (int ll = 0; ll < 3; ++ll) bh[ll] = b_h[ll * 128 + j_p];
    float wo0[6], wo1[6], bo[6];
    #pragma unroll
    for (int s = 0; s < 6; ++s) {
        wo0[s] = W_out[l * 6 + s];
        wo1[s] = W_out[(l + 64) * 6 + s];
        bo[s]  = b_out[s];
    }
    const int oaddr = 8 * (l >> 1) + 4 * (l >> 3) + (l & 1);  // + 2*rw at use

    float y[6];
    #pragma unroll
    for (int s = 0; s < 6; ++s) y[s] = y0[row * 6 + s];

    if (w < 4 && l == 0) {
        #pragma unroll
        for (int s = 0; s < 6; ++s) out[(size_t)row * kT * 6 + s] = y[s];
    }

    const float* mrow = meal + (size_t)row * kT;
    const float* vrow = tvns + (size_t)row * kT;

    auto dyn = [&](float t, const float* yc, float m, float v, float* d) {
        if (w < 4 && l == 0) {
            float* xb = &xbuf[w * 16];
            xb[0]=t;     xb[1]=yc[0]; xb[2]=yc[1]; xb[3]=yc[2];
            xb[4]=yc[3]; xb[5]=yc[4]; xb[6]=yc[5]; xb[7]=yc[3]; xb[8]=v;
        }
        __syncthreads();

        // ---- input layer 9->128: this thread produces h0[r_p][j_p]
        {
            float s = bin;
            #pragma unroll
            for (int k = 0; k < 9; ++k) s += xbuf[r_p * 16 + k] * win[k];
            hp0[waddr] = fast_tanh(s);
        }
        __syncthreads();

        // ---- 3 hidden layers 128->128
        #pragma unroll
        for (int ll = 0; ll < 3; ++ll) {
            const float* rb = (ll & 1) ? hp1 : hp0;
            float*       wb = (ll & 1) ? hp0 : hp1;

            f2 acc[4][4];   // [jj][r], packed over k-parity
            #pragma unroll
            for (int ka = 0; ka < 4; ++ka) {
                const int base = 36 * kc + 8 * ka;
                f4 q0 = *(const f4*)(rb + base);
                f4 q1 = *(const f4*)(rb + base + 4);
                f2 h0 = __builtin_shufflevector(q0, q0, 0, 1);
                f2 h1 = __builtin_shufflevector(q0, q0, 2, 3);
                f2 h2 = __builtin_shufflevector(q1, q1, 0, 1);
                f2 h3 = __builtin_shufflevector(q1, q1, 2, 3);
                #pragma unroll
                for (int jj = 0; jj < 4; ++jj) {
                    const f2 wv = wgt[ll][ka][jj];
                    if (ka == 0) {
                        acc[jj][0] = h0 * wv;
                        acc[jj][1] = h1 * wv;
                        acc[jj][2] = h2 * wv;
                        acc[jj][3] = h3 * wv;
                    } else {
                        acc[jj][0] = h0 * wv + acc[jj][0];
                        acc[jj][1] = h1 * wv + acc[jj][1];
                        acc[jj][2] = h2 * wv + acc[jj][2];
                        acc[jj][3] = h3 * wv + acc[jj][3];
                    }
                }
            }

            // horizontal add over k-parity; A indexed by out = (jj<<2)|r
            float A[16];
            #pragma unroll
            for (int o = 0; o < 16; ++o)
                A[o] = acc[o >> 2][o & 3].x + acc[o >> 2][o & 3].y;

            // 4-stage reduce-scatter over the 16 kc lanes (same jg group):
            // stage s keys out-bit s to kc-bit s. Lane ends with out = kc.
            float B[8];
            #pragma unroll
            for (int i = 0; i < 8; ++i) {
                float keep = pb0 ? A[2*i+1] : A[2*i];
                float give = pb0 ? A[2*i]   : A[2*i+1];
                B[i] = keep + dpp_xor1(give);
            }
            float C[4];
            #pragma unroll
            for (int i = 0; i < 4; ++i) {
                float keep = pb1 ? B[2*i+1] : B[2*i];
                float give = pb1 ? B[2*i]   : B[2*i+1];
                C[i] = keep + dpp_xor2(give);
            }
            float D[2];
            #pragma unroll
            for (int i = 0; i < 2; ++i) {
                float keep = pb2 ? C[2*i+1] : C[2*i];
                float give = pb2 ? C[2*i]   : C[2*i+1];
                D[i] = keep + swz<0x101F>(give);   // xor4
            }
            float keep = pb3 ? D[1] : D[0];
            float give = pb3 ? D[0] : D[1];
            float S = keep + swz<0x201F>(give);     // xor8

            wb[waddr] = fast_tanh(S + bh[ll]);
            __syncthreads();
        }

        // ---- output layer 128->6 for this wave's row; h3 lives in hp1
        float hA = hp1[oaddr + 2 * rw];
        float hB = hp1[oaddr + 2 * rw + 288];
        float p[6];
        #pragma unroll
        for (int s = 0; s < 6; ++s) {
            float ps = hA * wo0[s] + hB * wo1[s];
            ps += dpp_xor1(ps);
            ps += dpp_xor2(ps);
            ps = ps + swz<0x101F>(ps);
            ps = ps + swz<0x201F>(ps);
            ps = ps + swz<0x401F>(ps);
            ps += __shfl_xor(ps, 32);
            p[s] = ps;
        }

        const float G = yc[0], I = yc[1], N = yc[2], L = yc[3], GE = yc[4], F = yc[5];
        d[0] = -0.01f*I*G + 0.05f*GE                                    + p[0] + bo[0];
        d[1] = (G/(100.0f+G))*(1.0f + 2.0f*L/(5.0f+L)) - 0.1f*I         + p[1] + bo[1];
        d[2] = -0.05f*N                                                 + p[2] + bo[2];
        d[3] = 0.05f*GE - 0.2f*L                                        + p[3] + bo[3];
        d[4] = m - 0.05f*GE                                             + p[4] + bo[4];
        d[5] = -0.01f*I*F                                               + p[5] + bo[5];
    };

    for (int i = 0; i < kT - 1; ++i) {
        const float t0 = t_span[i], t1 = t_span[i + 1];
        const float dt = t1 - t0;
        const float m0 = mrow[i], m1 = mrow[i + 1];
        const float v0 = vrow[i], v1 = vrow[i + 1];
        const float tm = t0 + 0.5f * dt;
        const float mm = 0.5f * (m0 + m1), vm = 0.5f * (v0 + v1);

        float d[6], ksum[6], yc[6];

        dyn(t0, y, m0, v0, d);
        #pragma unroll
        for (int s = 0; s < 6; ++s) { ksum[s] = d[s]; yc[s] = y[s] + 0.5f * dt * d[s]; }
        dyn(tm, yc, mm, vm, d);
        #pragma unroll
        for (int s = 0; s < 6; ++s) { ksum[s] += 2.0f * d[s]; yc[s] = y[s] + 0.5f * dt * d[s]; }
        dyn(tm, yc, mm, vm, d);
        #pragma unroll
        for (int s = 0; s < 6; ++s) { ksum[s] += 2.0f * d[s]; yc[s] = y[s] + dt * d[s]; }
        dyn(t1, yc, m1, v1, d);
        #pragma unroll
        for (int s = 0; s < 6; ++s) {
            ksum[s] += d[s];
            y[s] += (dt * (1.0f / 6.0f)) * ksum[s];
        }

        if (w < 4 && l == 0) {
            #pragma unroll
            for (int s = 0; s < 6; ++s)
                out[((size_t)row * kT + (i + 1)) * 6 + s] = y[s];
        }
    }
}

} // namespace

extern "C" void kernel_launch(void* const* d_in, const int* in_sizes, int n_in,
                              void* d_out, int out_size, void* d_ws, size_t ws_size,
                              hipStream_t stream) {
    const float* y0     = (const float*)d_in[0];
    const float* t_span = (const float*)d_in[1];
    const float* meal   = (const float*)d_in[2];
    const float* tvns   = (const float*)d_in[3];
    const float* W_in   = (const float*)d_in[4];
    const float* b_in   = (const float*)d_in[5];
    const float* W_h    = (const float*)d_in[6];
    const float* b_h    = (const float*)d_in[7];
    const float* W_out  = (const float*)d_in[8];
    const float* b_out  = (const float*)d_in[9];
    float* out          = (float*)d_out;

    hipLaunchKernelGGL(hybrid_ode_kernel, dim3(256), dim3(512), 0, stream,
                       y0, t_span, meal, tvns,
                       W_in, b_in, W_h, b_h, W_out, b_out, out);
}